// Round 4
// baseline (535.585 us; speedup 1.0000x reference)
//
#include <hip/hip_runtime.h>
#include <hip/hip_bf16.h>

#define LYR 4
#define NH  8
#define DM  512
#define DHD 64
#define DFF 2048
#define BB  2
#define SSL 2048
#define NROWS (BB*SSL)   // 4096

typedef unsigned short u16;
typedef __attribute__((ext_vector_type(8))) short bf16x8;
typedef __attribute__((ext_vector_type(4))) float f32x4;
typedef __attribute__((ext_vector_type(4))) unsigned int u32x4;

__device__ __forceinline__ u16 f2bf(float f) {
    union { float f; unsigned u; } v; v.f = f;
    unsigned r = v.u + 0x7FFFu + ((v.u >> 16) & 1u);
    return (u16)(r >> 16);
}
__device__ __forceinline__ float bf2f(u16 b) {
    union { unsigned u; float f; } v; v.u = ((unsigned)b) << 16;
    return v.f;
}
// XOR-swizzled LDS index for [*][64]-u16 (128B-row) tiles, 16B granules.
__device__ __forceinline__ int swz(int row, int col) {
    return row * 64 + (col & 7) + ((((col >> 3) ^ row) & 7) << 3);
}
// same for [*][128]-u16 (256B-row) tiles, 16 slots
__device__ __forceinline__ int swzP(int row, int col) {
    return row * 128 + (col & 7) + ((((col >> 3) ^ row) & 15) << 3);
}
// async global->LDS, 16B per lane; LDS dest = wave-uniform base + lane*16
__device__ __forceinline__ void gload16(const u16* g, u16* l) {
    __builtin_amdgcn_global_load_lds(
        (const __attribute__((address_space(1))) unsigned int*)g,
        (__attribute__((address_space(3))) unsigned int*)l, 16, 0, 0);
}

// ---------------- precompute kernels ----------------

__global__ __launch_bounds__(256) void xpos_tables(float* __restrict__ tab) {
    const int idx = blockIdx.x * 256 + threadIdx.x;  // 2048*32
    const int s = idx >> 5, j = idx & 31;
    const float base = (2.f * j + 0.4f * 64.f) / (1.4f * 64.f);
    const float invf = powf(10000.f, -(float)j / 32.f);
    const float ang = (float)s * invf;
    const float scq = powf(base, (float)s / 512.f);
    tab[idx]          = sinf(ang);
    tab[idx + 65536]  = cosf(ang);
    tab[idx + 131072] = scq;
    tab[idx + 196608] = 1.f / scq;
}

// WQ/WK/WV (l,h,512,64) f32 -> WBT[l] rows (which*512 + h*64 + e), cols d (bf16, Bt layout)
__global__ __launch_bounds__(256)
void prep_qkv(const float* __restrict__ WQp, const float* __restrict__ WKp,
              const float* __restrict__ WVp, u16* __restrict__ WBT) {
    const int dt = blockIdx.x;                       // 0..7 d-tile
    const int h = blockIdx.y & 7, which = blockIdx.y >> 3;
    const int l = blockIdx.z;
    const float* W = (which == 0 ? WQp : which == 1 ? WKp : WVp);
    const float* ip = W + ((size_t)(l * 8 + h)) * (512 * 64);
    u16* op = WBT + (size_t)l * (2048 * 512) + (size_t)(which * 512 + h * 64) * 512;
    __shared__ u16 tile[64 * 72];
    const int t = threadIdx.x, rr = t >> 2, cc = (t & 3) * 16;
    const float* src = ip + (size_t)(dt * 64 + rr) * 64 + cc;
#pragma unroll
    for (int i = 0; i < 16; ++i) tile[rr * 72 + cc + i] = f2bf(src[i]);
    __syncthreads();
    u16 tmp[16] __attribute__((aligned(16)));
#pragma unroll
    for (int i = 0; i < 16; ++i) tmp[i] = tile[(cc + i) * 72 + rr];
    u16* dst = op + (size_t)rr * 512 + dt * 64 + cc;
    *(u32x4*)&dst[0] = *(const u32x4*)&tmp[0];
    *(u32x4*)&dst[8] = *(const u32x4*)&tmp[8];
}

// generic f32 (R,C) row-major -> bf16 out (C,R) row-major, per-layer z
__global__ __launch_bounds__(256)
void prep_t(const float* __restrict__ in, u16* __restrict__ out, int R, int C,
            long long in_ls, long long out_ls) {
    const float* ip = in + (size_t)blockIdx.z * in_ls;
    u16* op = out + (size_t)blockIdx.z * out_ls;
    const int r0 = blockIdx.x * 64, c0t = blockIdx.y * 64;
    __shared__ u16 tile[64 * 72];
    const int t = threadIdx.x, rr = t >> 2, cc = (t & 3) * 16;
    const float* src = ip + (size_t)(r0 + rr) * C + c0t + cc;
#pragma unroll
    for (int i = 0; i < 16; ++i) tile[rr * 72 + cc + i] = f2bf(src[i]);
    __syncthreads();
    u16 tmp[16] __attribute__((aligned(16)));
#pragma unroll
    for (int i = 0; i < 16; ++i) tmp[i] = tile[(cc + i) * 72 + rr];
    u16* dst = op + (size_t)(c0t + rr) * R + r0 + cc;
    *(u32x4*)&dst[0] = *(const u32x4*)&tmp[0];
    *(u32x4*)&dst[8] = *(const u32x4*)&tmp[8];
}

// ---------------- LayerNorm (one wave per 512-wide row) ----------------
__global__ __launch_bounds__(256)
void ln_kernel(const float* __restrict__ x, const float* __restrict__ wt,
               const float* __restrict__ bs, u16* __restrict__ out) {
    const int row = blockIdx.x * 4 + (threadIdx.x >> 6);
    const int lane = threadIdx.x & 63;
    const float* xr = x + (size_t)row * DM + lane * 8;
    float v[8];
    *(float4*)&v[0] = *(const float4*)&xr[0];
    *(float4*)&v[4] = *(const float4*)&xr[4];
    float s = 0.f, s2 = 0.f;
#pragma unroll
    for (int i = 0; i < 8; ++i) { s += v[i]; s2 += v[i] * v[i]; }
#pragma unroll
    for (int m = 1; m < 64; m <<= 1) {
        s  += __shfl_xor(s, m, 64);
        s2 += __shfl_xor(s2, m, 64);
    }
    const float mu = s * (1.f / DM);
    const float rs = rsqrtf(s2 * (1.f / DM) - mu * mu + 1e-5f);
    const int e0 = lane * 8;
    u16 o[8] __attribute__((aligned(16)));
#pragma unroll
    for (int i = 0; i < 8; ++i)
        o[i] = f2bf((v[i] - mu) * rs * wt[e0 + i] + bs[e0 + i]);
    *(u32x4*)&out[(size_t)row * DM + e0] = *(const u32x4*)o;
}

// ---------------- bf16 GEMM v2: C = A(MxK,row) * Bt(NxK,row)^T ----------------
// 512 threads (8 waves, 2M x 4N), BN=256, double-buffered global_load_lds,
// stage-at-top + single barrier per K-tile (m248-minimal deep pipeline),
// setprio around MFMA cluster, XCD-chunked block mapping.
// EPI 0: out bf16 raw | 1: f32 = acc + res | 2: bf16 = gelu(acc+bias) | 3: f32 = acc+bias+res
template <int BM, int EPI>
__global__ __launch_bounds__(512, 2)
void gemm_v2(const u16* __restrict__ A, const u16* __restrict__ Bt,
             u16* __restrict__ obf, float* __restrict__ of32,
             const float* __restrict__ res, const float* __restrict__ bias,
             int M, int N, int K) {
    constexpr int BN = 256;
    constexpr int FM = BM / 32;        // row-frags per wave (per-wave rows BM/2)
    constexpr int ART = BM / 64;       // A staging rounds of 64 rows
    __shared__ __align__(16) u16 As[2][BM * 64];
    __shared__ __align__(16) u16 Bs[2][BN * 64];
    const int t = threadIdx.x;
    const int lane = t & 63, w = t >> 6;
    const int wrm = w >> 2, wcn = w & 3;
    const int fr = lane & 15, fq = lane >> 4;
    const int nX = N / BN;
    const int nwg = (M / BM) * nX;
    // XCD-chunked bijective swizzle (nwg % 8 == 0 for all our launches)
    const int swzid = (blockIdx.x & 7) * (nwg >> 3) + (blockIdx.x >> 3);
    const int m0 = (swzid / nX) * BM, n0 = (swzid % nX) * BN;
    const int sr = lane >> 3, sg = lane & 7;   // staging row-in-8 / granule
    const int kt = K >> 6;

    auto stage = [&](int tile, int slot) {
        const int k0 = tile << 6;
#pragma unroll
        for (int rb = 0; rb < ART; ++rb) {
            const int row = rb * 64 + w * 8 + sr;
            const int cc = sg ^ (row & 7);
            gload16(&A[(size_t)(m0 + row) * K + k0 + cc * 8],
                    &As[slot][(rb * 64 + w * 8) * 64]);
        }
#pragma unroll
        for (int rb = 0; rb < 4; ++rb) {
            const int row = rb * 64 + w * 8 + sr;
            const int cc = sg ^ (row & 7);
            gload16(&Bt[(size_t)(n0 + row) * K + k0 + cc * 8],
                    &Bs[slot][(rb * 64 + w * 8) * 64]);
        }
    };

    f32x4 acc[FM][4] = {};
    stage(0, 0);
    asm volatile("s_waitcnt vmcnt(0)" ::: "memory");
    __builtin_amdgcn_s_barrier();

    for (int tile = 0; tile < kt; ++tile) {
        const int s = tile & 1;
        if (tile + 1 < kt) stage(tile + 1, s ^ 1);   // issue BEFORE compute
        const u16* Ac = As[s];
        const u16* Bc = Bs[s];
        bf16x8 bv[4][2];
#pragma unroll
        for (int j = 0; j < 4; ++j)
#pragma unroll
            for (int ks = 0; ks < 2; ++ks)
                bv[j][ks] = *(const bf16x8*)&Bc[swz(wcn * 64 + j * 16 + fr, ks * 32 + fq * 8)];
        __builtin_amdgcn_s_setprio(1);
#pragma unroll
        for (int q = 0; q < FM; ++q) {
            const int ar = wrm * (BM / 2) + q * 16 + fr;
            bf16x8 av0 = *(const bf16x8*)&Ac[swz(ar, fq * 8)];
            bf16x8 av1 = *(const bf16x8*)&Ac[swz(ar, 32 + fq * 8)];
#pragma unroll
            for (int j = 0; j < 4; ++j) {
                acc[q][j] = __builtin_amdgcn_mfma_f32_16x16x32_bf16(av0, bv[j][0], acc[q][j], 0, 0, 0);
                acc[q][j] = __builtin_amdgcn_mfma_f32_16x16x32_bf16(av1, bv[j][1], acc[q][j], 0, 0, 0);
            }
        }
        __builtin_amdgcn_s_setprio(0);
        asm volatile("s_waitcnt lgkmcnt(0)" ::: "memory");   // our slot-s reads retired
        __builtin_amdgcn_sched_barrier(0);
        if (tile + 1 < kt)
            asm volatile("s_waitcnt vmcnt(0)" ::: "memory"); // next tile landed
        __builtin_amdgcn_s_barrier();
    }

#pragma unroll
    for (int q = 0; q < FM; ++q)
#pragma unroll
        for (int j = 0; j < 4; ++j)
#pragma unroll
            for (int r = 0; r < 4; ++r) {
                const int m = m0 + wrm * (BM / 2) + q * 16 + fq * 4 + r;
                const int n = n0 + wcn * 64 + j * 16 + fr;
                const size_t idx = (size_t)m * N + n;
                float v = acc[q][j][r];
                if constexpr (EPI == 0) {
                    obf[idx] = f2bf(v);
                } else if constexpr (EPI == 1) {
                    of32[idx] = v + res[idx];
                } else if constexpr (EPI == 2) {
                    float tt = v + bias[n];
                    obf[idx] = f2bf(0.5f * tt * (1.f + erff(tt * 0.7071067811865475f)));
                } else {
                    of32[idx] = v + bias[n] + res[idx];
                }
            }
}

// ---------------- xPos rotate + relayout (Q,K -> (b,h,s,e); V -> (b,h,e,s)) ----------------
__global__ __launch_bounds__(256)
void xpos_relayout(const u16* __restrict__ qkvg, const float* __restrict__ tab,
                   u16* __restrict__ Qb, u16* __restrict__ Kb, u16* __restrict__ Vt) {
    const int st = blockIdx.x, h = blockIdx.y, b = blockIdx.z;
    const int t = threadIdx.x;
    const int r = t >> 2;
    const int sg = st * 64 + r;
    const size_t rawrow = ((size_t)(b * SSL + sg)) * 2048;
    const size_t qrow = ((size_t)((b * NH + h) * SSL + sg)) * 64;
    const int j0 = (t & 3) * 8;
#pragma unroll
    for (int jj = 0; jj < 8; ++jj) {
        const int j = j0 + jj;
        const float sn = tab[sg * 32 + j];
        const float cs = tab[sg * 32 + j + 65536];
        const float sq = tab[sg * 32 + j + 131072];
        const float sk2 = tab[sg * 32 + j + 196608];
        unsigned rawq = *(const unsigned*)&qkvg[rawrow + h * 64 + 2 * j];
        float q0 = bf2f((u16)(rawq & 0xffff)), q1 = bf2f((u16)(rawq >> 16));
        float o0 = (q0 * cs - q1 * sn) * sq;
        float o1 = (q1 * cs + q0 * sn) * sq;
        *(unsigned*)&Qb[qrow + 2 * j] = ((unsigned)f2bf(o1) << 16) | (unsigned)f2bf(o0);
        unsigned rawk = *(const unsigned*)&qkvg[rawrow + 512 + h * 64 + 2 * j];
        float k0 = bf2f((u16)(rawk & 0xffff)), k1 = bf2f((u16)(rawk >> 16));
        float p0 = (k0 * cs - k1 * sn) * sk2;
        float p1 = (k1 * cs + k0 * sn) * sk2;
        *(unsigned*)&Kb[qrow + 2 * j] = ((unsigned)f2bf(p1) << 16) | (unsigned)f2bf(p0);
    }
    __shared__ __align__(16) u16 vt[64 * 72];
    const int c0 = (t & 3) * 16;
    *(u32x4*)&vt[r * 72 + c0]     = *(const u32x4*)&qkvg[rawrow + 1024 + h * 64 + c0];
    *(u32x4*)&vt[r * 72 + c0 + 8] = *(const u32x4*)&qkvg[rawrow + 1024 + h * 64 + c0 + 8];
    __syncthreads();
    u16 tmp[16] __attribute__((aligned(16)));
#pragma unroll
    for (int i = 0; i < 16; ++i) tmp[i] = vt[(c0 + i) * 72 + r];
    u16* dst = Vt + ((size_t)((b * NH + h) * 64 + r)) * SSL + st * 64 + c0;
    *(u32x4*)&dst[0] = *(const u32x4*)&tmp[0];
    *(u32x4*)&dst[8] = *(const u32x4*)&tmp[8];
}

// ---------------- fused retention + groupnorm + silu gate ----------------
// 8 waves, KVBLK=128, double-buffered global_load_lds staging, 2 barriers/iter,
// factored decay mask, decay-window truncation, XCD-chunked bh mapping.
__global__ __launch_bounds__(512)
void retention(const u16* __restrict__ Qb, const u16* __restrict__ Kb,
               const u16* __restrict__ Vt, const u16* __restrict__ qkvg,
               const float* __restrict__ gnw, const float* __restrict__ gnb,
               u16* __restrict__ zb) {
    extern __shared__ __align__(16) char smem[];
    u16* KsB = (u16*)smem;                 // [2][128*64]  32KB
    u16* VsB = (u16*)(smem + 32768);       // [2][64*128]  32KB
    u16* Qs  = (u16*)(smem + 65536);       // [64*64]       8KB
    u16* Ps  = (u16*)(smem + 73728);       // [64*128]     16KB

    // XCD chunking: each XCD owns 2 whole (b,h) pairs -> K/V L2-resident
    const int logical = (blockIdx.x & 7) * 64 + (blockIdx.x >> 3);
    const int bh = logical >> 5;
    const int qt = 31 - (logical & 31);    // LPT: long blocks first
    const int h = bh & 7, b = bh >> 3;
    const int t = threadIdx.x;
    const int lane = t & 63, w = t >> 6;
    const int fr = lane & 15, fq = lane >> 4;
    const int wr = w & 1, wc2 = w >> 1;    // QK: S quadrant (wr, wc2) of 64x128
    const int oc = wc2 & 1, th = w >> 2;   // PV: O quadrant (wr, oc), t-half th

    const float gamma = 1.f - expf(-3.4657359f + (float)h * -0.39608410f);
    const float lgam = log2f(gamma);
    const float dlim = 19.931568f / (-lgam);       // gamma^d < 1e-6 beyond
    const int jt_last = (qt * 64 + 63) >> 7;
    int jt_min = 0;
    {
        const float need = (float)(qt * 64 - 127) - dlim;
        if (need > 0.f) jt_min = (int)ceilf(need * (1.f / 128.f));
        if (jt_min > jt_last) jt_min = jt_last;
        if (jt_min < 0) jt_min = 0;
    }

    float rowf[2][4], colf[2];
#pragma unroll
    for (int i = 0; i < 2; ++i)
#pragma unroll
        for (int rr = 0; rr < 4; ++rr)
            rowf[i][rr] = exp2f((float)(wr * 32 + i * 16 + fq * 4 + rr) * lgam);
#pragma unroll
    for (int j = 0; j < 2; ++j)
        colf[j] = exp2f(-(float)(wc2 * 32 + j * 16 + fr) * lgam);

    const size_t bh2048 = (size_t)bh * 2048;
    const int lr8 = lane >> 3, ls8 = lane & 7;
    const int lr16 = lane >> 4, ls16 = lane & 15;

    // stage Q once (64 rows x 128B)
    {
        const int row = w * 8 + lr8;
        const int cc = ls8 ^ (row & 7);
        gload16(&Qb[(bh2048 + qt * 64 + row) * 64 + cc * 8], &Qs[w * 512]);
    }

    f32x4 oacc[2][2] = {};
    int cur = 0;
    // prologue stage
    {
        const int jt = jt_min;
        u16* Kd = KsB; u16* Vd = VsB;
#pragma unroll
        for (int q = 0; q < 2; ++q) {
            const int row = q * 64 + w * 8 + lr8;
            const int cc = ls8 ^ (row & 7);
            gload16(&Kb[(bh2048 + jt * 128 + row) * 64 + cc * 8], &Kd[(q * 64 + w * 8) * 64]);
        }
#pragma unroll
        for (int q = 0; q < 2; ++q) {
            const int row = w * 8 + q * 4 + lr16;
            const int cc = ls16 ^ (row & 15);
            gload16(&Vt[((size_t)bh * 64 + row) * 2048 + jt * 128 + cc * 8], &Vd[(w * 8 + q * 4) * 128]);
        }
    }

    for (int jt = jt_min; jt <= jt_last; ++jt) {
        __syncthreads();                       // buf[cur] staged; P consumed
        if (jt < jt_last) {                    // prefetch next tile into buf[cur^1]
            const int nb = cur ^ 1;
            u16* Kd = KsB + nb * 8192;
            u16* Vd = VsB + nb * 8192;
#pragma unroll
            for (int q = 0; q < 2; ++q) {
                const int row = q * 64 + w * 8 + lr8;
                const int cc = ls8 ^ (row & 7);
                gload16(&Kb[(bh2048 + (jt + 1) * 128 + row) * 64 + cc * 8], &Kd[(q * 64 + w * 8) * 64]);
            }
#pragma unroll
            for (int q = 0; q < 2; ++q) {
                const int row = w * 8 + q * 4 + lr16;
                const int cc = ls16 ^ (row & 15);
                gload16(&Vt[((size_t)bh * 64 + row) * 2048 + (jt + 1) * 128 + cc * 8], &Vd[(w * 8 + q * 4) * 128]);
            }
        }
        const u16* Kc = KsB + cur * 8192;
        f32x4 sac[2][2] = {};
#pragma unroll
        for (int ks = 0; ks < 2; ++ks) {
            bf16x8 qa[2], kb[2];
#pragma unroll
            for (int i = 0; i < 2; ++i)
                qa[i] = *(const bf16x8*)&Qs[swz(wr * 32 + i * 16 + fr, ks * 32 + fq * 8)];
#pragma unroll
            for (int j = 0; j < 2; ++j)
                kb[j] = *(const bf16x8*)&Kc[swz(wc2 * 32 + j * 16 + fr, ks * 32 + fq * 8)];
#pragma unroll
            for (int i = 0; i < 2; ++i)
#pragma unroll
                for (int j = 0; j < 2; ++j)
                    sac[i][j] = __builtin_amdgcn_mfma_f32_16x16x32_bf16(qa[i], kb[j], sac[i][j], 0, 0, 0);
        }
        const float sc = exp2f((float)(qt * 64 - jt * 128) * lgam);
        const bool diag = (jt == jt_last);
#pragma unroll
        for (int i = 0; i < 2; ++i)
#pragma unroll
            for (int j = 0; j < 2; ++j)
#pragma unroll
                for (int rr = 0; rr < 4; ++rr) {
                    float m = sc * rowf[i][rr] * colf[j];
                    if (diag) {
                        const int d = (qt * 64 + wr * 32 + i * 16 + fq * 4 + rr)
                                    - (jt * 128 + wc2 * 32 + j * 16 + fr);
                        if (d < 0) m = 0.f;
                    }
                    Ps[swzP(wr * 32 + i * 16 + fq * 4 + rr, wc2 * 32 + j * 16 + fr)] =
                        f2bf(sac[i][j][rr] * m);
                }
        __syncthreads();                       // P visible
        const u16* Vc = VsB + cur * 8192;
#pragma unroll
        for (int ks = 0; ks < 2; ++ks) {
            const int tcol = th * 64 + ks * 32 + fq * 8;
            bf16x8 pa[2], vb[2];
#pragma unroll
            for (int i = 0; i < 2; ++i)
                pa[i] = *(const bf16x8*)&Ps[swzP(wr * 32 + i * 16 + fr, tcol)];
#pragma unroll
            for (int j = 0; j < 2; ++j)
                vb[j] = *(const bf16x8*)&Vc[swzP(oc * 32 + j * 16 + fr, tcol)];
#pragma unroll
            for (int i = 0; i < 2; ++i)
#pragma unroll
                for (int j = 0; j < 2; ++j)
                    oacc[i][j] = __builtin_amdgcn_mfma_f32_16x16x32_bf16(pa[i], vb[j], oacc[i][j], 0, 0, 0);
        }
        cur ^= 1;
    }

    // ---- cross-t-half reduce + groupnorm + gate ----
    __syncthreads();
    float* Of = (float*)smem;                 // [64][66] f32, aliases K buffers
    if (th == 1) {
#pragma unroll
        for (int i = 0; i < 2; ++i)
#pragma unroll
            for (int j = 0; j < 2; ++j)
#pragma unroll
                for (int rr = 0; rr < 4; ++rr)
                    Of[(wr * 32 + i * 16 + fq * 4 + rr) * 66 + oc * 32 + j * 16 + fr] = oacc[i][j][rr];
    }
    __syncthreads();
    if (th == 0) {
#pragma unroll
        for (int i = 0; i < 2; ++i)
#pragma unroll
            for (int j = 0; j < 2; ++j)
#pragma unroll
                for (int rr = 0; rr < 4; ++rr) {
                    const int idx = (wr * 32 + i * 16 + fq * 4 + rr) * 66 + oc * 32 + j * 16 + fr;
                    Of[idx] += oacc[i][j][rr];
                }
    }
    __syncthreads();
    const int row = t >> 3, c0 = (t & 7) * 8;
    float v[8];
    float s = 0.f, s2 = 0.f;
#pragma unroll
    for (int i = 0; i < 8; ++i) {
        v[i] = Of[row * 66 + c0 + i];
        s += v[i]; s2 += v[i] * v[i];
    }
    s  += __shfl_xor(s, 1, 64);  s  += __shfl_xor(s, 2, 64);  s  += __shfl_xor(s, 4, 64);
    s2 += __shfl_xor(s2, 1, 64); s2 += __shfl_xor(s2, 2, 64); s2 += __shfl_xor(s2, 4, 64);
    const float mu = s * (1.f / 64.f);
    const float rs = rsqrtf(s2 * (1.f / 64.f) - mu * mu + 1e-5f);
    const int sg = qt * 64 + row;
    u16 gv[8] __attribute__((aligned(16)));
    *(u32x4*)gv = *(const u32x4*)&qkvg[((size_t)(b * SSL + sg)) * 2048 + 1536 + h * 64 + c0];
    u16 ob[8] __attribute__((aligned(16)));
#pragma unroll
    for (int i = 0; i < 8; ++i) {
        const int dc = h * 64 + c0 + i;
        const float yn = (v[i] - mu) * rs * gnw[dc] + gnb[dc];
        const float g = bf2f(gv[i]);
        ob[i] = f2bf(yn * (g / (1.f + expf(-g))));
    }
    *(u32x4*)&zb[((size_t)(b * SSL + sg)) * 512 + h * 64 + c0] = *(const u32x4*)ob;
}

// ---------------- host ----------------
extern "C" void kernel_launch(void* const* d_in, const int* in_sizes, int n_in,
                              void* d_out, int out_size, void* d_ws, size_t ws_size,
                              hipStream_t stream) {
    const float* X    = (const float*)d_in[0];
    const float* WQ   = (const float*)d_in[1];
    const float* WK   = (const float*)d_in[2];
    const float* WV   = (const float*)d_in[3];
    const float* WG   = (const float*)d_in[4];
    const float* WO   = (const float*)d_in[5];
    const float* GNW  = (const float*)d_in[6];
    const float* GNB  = (const float*)d_in[7];
    const float* LN1W = (const float*)d_in[8];
    const float* LN1B = (const float*)d_in[9];
    const float* LN2W = (const float*)d_in[10];
    const float* LN2B = (const float*)d_in[11];
    const float* FW1  = (const float*)d_in[12];
    const float* FB1  = (const float*)d_in[13];
    const float* FW2  = (const float*)d_in[14];
    const float* FB2  = (const float*)d_in[15];

    char* ws = (char*)d_ws;
    size_t off = 0;
    auto alloc = [&](size_t n) { char* p = ws + off; off += (n + 255) & ~(size_t)255; return p; };

    u16*   WBT  = (u16*)alloc((size_t)LYR * 2048 * 512 * 2);
    u16*   WOT  = (u16*)alloc((size_t)LYR * 512 * 512 * 2);
    u16*   W1T  = (u16*)alloc((size_t)LYR * 2048 * 512 * 2);
    u16*   W2T  = (u16*)alloc((size_t)LYR * 512 * 2048 * 2);
    float* TAB  = (float*)alloc((size_t)4 * 2048 * 32 * 4);
    float* XB   = (float*)alloc((size_t)NROWS * DM * 4);
    u16*   XN   = (u16*)alloc((size_t)NROWS * DM * 2);
    u16*   QKVG = (u16*)alloc((size_t)NROWS * 2048 * 2);
    u16*   QBp  = (u16*)alloc((size_t)NROWS * DM * 2);
    u16*   KBp  = (u16*)alloc((size_t)NROWS * DM * 2);
    u16*   VTp  = (u16*)alloc((size_t)NROWS * DM * 2);
    u16*   ZB   = (u16*)alloc((size_t)NROWS * DM * 2);
    float* Y1   = (float*)alloc((size_t)NROWS * DM * 4);
    u16*   HB   = QBp;   // alias: QB dead after retention
    u16*   FF1  = QKVG;  // alias: QKVG dead after retention

    xpos_tables<<<256, 256, 0, stream>>>(TAB);
    prep_qkv<<<dim3(8, 24, LYR), 256, 0, stream>>>(WQ, WK, WV, WBT);
    prep_t<<<dim3(8, 8, LYR), 256, 0, stream>>>(WG, WBT + 1536 * 512, 512, 512,
                                                (long long)512 * 512, (long long)2048 * 512);
    prep_t<<<dim3(8, 8, LYR), 256, 0, stream>>>(WO, WOT, 512, 512,
                                                (long long)512 * 512, (long long)512 * 512);
    prep_t<<<dim3(8, 32, LYR), 256, 0, stream>>>(FW1, W1T, 512, 2048,
                                                 (long long)512 * 2048, (long long)2048 * 512);
    prep_t<<<dim3(32, 8, LYR), 256, 0, stream>>>(FW2, W2T, 2048, 512,
                                                 (long long)2048 * 512, (long long)512 * 2048);

    for (int l = 0; l < LYR; ++l) {
        const float* xsrc = (l == 0) ? X : XB;
        float* xdst = (l == LYR - 1) ? (float*)d_out : XB;
        ln_kernel<<<NROWS / 4, 256, 0, stream>>>(xsrc, LN1W + l * 512, LN1B + l * 512, XN);
        gemm_v2<128, 0><<<256, 512, 0, stream>>>(
            XN, WBT + (size_t)l * 2048 * 512, QKVG, nullptr, nullptr, nullptr, NROWS, 2048, 512);
        xpos_relayout<<<dim3(SSL / 64, NH, BB), 256, 0, stream>>>(QKVG, TAB, QBp, KBp, VTp);
        retention<<<512, 512, 90112, stream>>>(QBp, KBp, VTp, QKVG,
                                               GNW + l * 512, GNB + l * 512, ZB);
        gemm_v2<64, 1><<<128, 512, 0, stream>>>(
            ZB, WOT + (size_t)l * 512 * 512, nullptr, Y1, xsrc, nullptr, NROWS, 512, 512);
        ln_kernel<<<NROWS / 4, 256, 0, stream>>>(Y1, LN2W + l * 512, LN2B + l * 512, HB);
        gemm_v2<128, 2><<<256, 512, 0, stream>>>(
            HB, W1T + (size_t)l * 2048 * 512, FF1, nullptr, nullptr, FB1 + l * 2048, NROWS, 2048, 512);
        gemm_v2<64, 3><<<128, 512, 0, stream>>>(
            FF1, W2T + (size_t)l * 512 * 2048, nullptr, xdst, Y1, FB2 + l * 512, NROWS, 512, 2048);
    }
}

// Round 5
// 477.297 us; speedup vs baseline: 1.1221x; 1.1221x over previous
//
#include <hip/hip_runtime.h>
#include <hip/hip_bf16.h>

#define LYR 4
#define NH  8
#define DM  512
#define DHD 64
#define DFF 2048
#define BB  2
#define SSL 2048
#define NROWS (BB*SSL)   // 4096

typedef unsigned short u16;
typedef __attribute__((ext_vector_type(8))) short bf16x8;
typedef __attribute__((ext_vector_type(4))) float f32x4;
typedef __attribute__((ext_vector_type(4))) unsigned int u32x4;

__device__ __forceinline__ u16 f2bf(float f) {
    union { float f; unsigned u; } v; v.f = f;
    unsigned r = v.u + 0x7FFFu + ((v.u >> 16) & 1u);
    return (u16)(r >> 16);
}
__device__ __forceinline__ float bf2f(u16 b) {
    union { unsigned u; float f; } v; v.u = ((unsigned)b) << 16;
    return v.f;
}
// XOR-swizzled LDS index for [*][64]-u16 (128B-row) tiles, 16B granules.
__device__ __forceinline__ int swz(int row, int col) {
    return row * 64 + (col & 7) + ((((col >> 3) ^ row) & 7) << 3);
}
// same for [*][128]-u16 (256B-row) tiles, 16 slots
__device__ __forceinline__ int swzP(int row, int col) {
    return row * 128 + (col & 7) + ((((col >> 3) ^ row) & 15) << 3);
}
// async global->LDS, 16B per lane; LDS dest = wave-uniform base + lane*16
__device__ __forceinline__ void gload16(const u16* g, u16* l) {
    __builtin_amdgcn_global_load_lds(
        (const __attribute__((address_space(1))) unsigned int*)g,
        (__attribute__((address_space(3))) unsigned int*)l, 16, 0, 0);
}
template <int N> __device__ __forceinline__ void wait_vmcnt() {
    if constexpr (N == 0)      asm volatile("s_waitcnt vmcnt(0)" ::: "memory");
    else if constexpr (N == 6) asm volatile("s_waitcnt vmcnt(6)" ::: "memory");
    else if constexpr (N == 8) asm volatile("s_waitcnt vmcnt(8)" ::: "memory");
    else static_assert(N == 0 || N == 6 || N == 8, "unsupported vmcnt");
}
__device__ __forceinline__ void block_barrier() {
    __builtin_amdgcn_s_barrier();
    asm volatile("" ::: "memory");
}

// ---------------- precompute kernels ----------------

// packed per-(s, jpair) xPos table: {sin, cos, scale_q, scale_k}
__global__ __launch_bounds__(256) void xpos_tables(float4* __restrict__ tab4) {
    const int idx = blockIdx.x * 256 + threadIdx.x;  // 2048*32
    const int s = idx >> 5, j = idx & 31;
    const float base = (2.f * j + 0.4f * 64.f) / (1.4f * 64.f);
    const float invf = powf(10000.f, -(float)j / 32.f);
    const float ang = (float)s * invf;
    const float scq = powf(base, (float)s / 512.f);
    tab4[idx] = make_float4(sinf(ang), cosf(ang), scq, 1.f / scq);
}

// WQ/WK/WV (l,h,512,64) f32 -> WBT[l] rows (which*512 + h*64 + e), cols d (bf16, Bt layout)
__global__ __launch_bounds__(256)
void prep_qkv(const float* __restrict__ WQp, const float* __restrict__ WKp,
              const float* __restrict__ WVp, u16* __restrict__ WBT) {
    const int dt = blockIdx.x;                       // 0..7 d-tile
    const int h = blockIdx.y & 7, which = blockIdx.y >> 3;
    const int l = blockIdx.z;
    const float* W = (which == 0 ? WQp : which == 1 ? WKp : WVp);
    const float* ip = W + ((size_t)(l * 8 + h)) * (512 * 64);
    u16* op = WBT + (size_t)l * (2048 * 512) + (size_t)(which * 512 + h * 64) * 512;
    __shared__ u16 tile[64 * 72];
    const int t = threadIdx.x, rr = t >> 2, cc = (t & 3) * 16;
    const float* src = ip + (size_t)(dt * 64 + rr) * 64 + cc;
#pragma unroll
    for (int i = 0; i < 16; ++i) tile[rr * 72 + cc + i] = f2bf(src[i]);
    __syncthreads();
    u16 tmp[16] __attribute__((aligned(16)));
#pragma unroll
    for (int i = 0; i < 16; ++i) tmp[i] = tile[(cc + i) * 72 + rr];
    u16* dst = op + (size_t)rr * 512 + dt * 64 + cc;
    *(u32x4*)&dst[0] = *(const u32x4*)&tmp[0];
    *(u32x4*)&dst[8] = *(const u32x4*)&tmp[8];
}

// generic f32 (R,C) row-major -> bf16 out (C,R) row-major, per-layer z
__global__ __launch_bounds__(256)
void prep_t(const float* __restrict__ in, u16* __restrict__ out, int R, int C,
            long long in_ls, long long out_ls) {
    const float* ip = in + (size_t)blockIdx.z * in_ls;
    u16* op = out + (size_t)blockIdx.z * out_ls;
    const int r0 = blockIdx.x * 64, c0t = blockIdx.y * 64;
    __shared__ u16 tile[64 * 72];
    const int t = threadIdx.x, rr = t >> 2, cc = (t & 3) * 16;
    const float* src = ip + (size_t)(r0 + rr) * C + c0t + cc;
#pragma unroll
    for (int i = 0; i < 16; ++i) tile[rr * 72 + cc + i] = f2bf(src[i]);
    __syncthreads();
    u16 tmp[16] __attribute__((aligned(16)));
#pragma unroll
    for (int i = 0; i < 16; ++i) tmp[i] = tile[(cc + i) * 72 + rr];
    u16* dst = op + (size_t)(c0t + rr) * R + r0 + cc;
    *(u32x4*)&dst[0] = *(const u32x4*)&tmp[0];
    *(u32x4*)&dst[8] = *(const u32x4*)&tmp[8];
}

// ---------------- LayerNorm (one wave per 512-wide row) ----------------
__global__ __launch_bounds__(256)
void ln_kernel(const float* __restrict__ x, const float* __restrict__ wt,
               const float* __restrict__ bs, u16* __restrict__ out) {
    const int row = blockIdx.x * 4 + (threadIdx.x >> 6);
    const int lane = threadIdx.x & 63;
    const float* xr = x + (size_t)row * DM + lane * 8;
    float v[8];
    *(float4*)&v[0] = *(const float4*)&xr[0];
    *(float4*)&v[4] = *(const float4*)&xr[4];
    float s = 0.f, s2 = 0.f;
#pragma unroll
    for (int i = 0; i < 8; ++i) { s += v[i]; s2 += v[i] * v[i]; }
#pragma unroll
    for (int m = 1; m < 64; m <<= 1) {
        s  += __shfl_xor(s, m, 64);
        s2 += __shfl_xor(s2, m, 64);
    }
    const float mu = s * (1.f / DM);
    const float rs = rsqrtf(s2 * (1.f / DM) - mu * mu + 1e-5f);
    const int e0 = lane * 8;
    u16 o[8] __attribute__((aligned(16)));
#pragma unroll
    for (int i = 0; i < 8; ++i)
        o[i] = f2bf((v[i] - mu) * rs * wt[e0 + i] + bs[e0 + i]);
    *(u32x4*)&out[(size_t)row * DM + e0] = *(const u32x4*)o;
}

// ---------------- generic bf16 GEMM: C = A(MxK,row) * Bt(NxK,row)^T ----------------
// round-3 skeleton: global_load_lds double-buffer, counted vmcnt(6) (never 0
// mid-loop), raw s_barrier, XCD-chunked block mapping.
// EPI 0: bf16 raw | 1: f32 acc+res | 2: bf16 gelu(acc+bias) | 3: f32 acc+bias+res
// EPI 4: fused QKVG epilogue (xPos rotate Q/K, transpose V, plain G)
template <int BM, int BN, int EPI>
__global__ __launch_bounds__(256)
void gemm_bt(const u16* __restrict__ A, const u16* __restrict__ Bt,
             u16* __restrict__ obf, float* __restrict__ of32,
             const float* __restrict__ res, const float* __restrict__ bias,
             u16* __restrict__ qb, u16* __restrict__ kb, u16* __restrict__ vt,
             u16* __restrict__ gb, const float4* __restrict__ tab4,
             int M, int N, int K) {
    constexpr int FM = BM / 32, FN = BN / 32;
    constexpr int LPS = BM / 32 + BN / 32;   // gload_lds per thread per K-step
    static_assert(LPS == 6, "vmcnt template expects 6");
    __shared__ __align__(16) u16 As[2][BM * 64];
    __shared__ __align__(16) u16 Bs[2][BN * 64];
    const int t = threadIdx.x;
    const int lane = t & 63, w4 = t >> 6;
    const int wr = w4 >> 1, wc = w4 & 1;
    const int fr = lane & 15, fq = lane >> 4;
    // XCD-chunked bijective swizzle: nwg % 8 == 0 for all our launches
    const int nX = N / BN;
    const int nwg = (M / BM) * nX;
    const int swzid = (blockIdx.x & 7) * (nwg >> 3) + (blockIdx.x >> 3);
    const int m0 = (swzid / nX) * BM, n0 = (swzid % nX) * BN;
    const int lr = lane >> 3;          // staging row within 8-row group
    const int ls = lane & 7;           // staging 16B slot
    const int nsteps = K >> 6;

    auto stage = [&](int step, int slot) {
        const int k0 = step << 6;
#pragma unroll
        for (int q = 0; q < BM / 32; ++q) {
            const int ib = q * 4 + w4;
            const int row = ib * 8 + lr;
            const int cc = ls ^ (row & 7);
            gload16(&A[(size_t)(m0 + row) * K + k0 + cc * 8], &As[slot][ib * 512]);
        }
#pragma unroll
        for (int q = 0; q < BN / 32; ++q) {
            const int ib = q * 4 + w4;
            const int row = ib * 8 + lr;
            const int cc = ls ^ (row & 7);
            gload16(&Bt[(size_t)(n0 + row) * K + k0 + cc * 8], &Bs[slot][ib * 512]);
        }
    };

    f32x4 acc[FM][FN] = {};
    stage(0, 0);
    stage(1, 1);
    for (int st = 0; st < nsteps; ++st) {
        // own-wave tile-st loads complete (tile st+1 stays in flight)
        if (st + 1 < nsteps) wait_vmcnt<LPS>(); else wait_vmcnt<0>();
        __builtin_amdgcn_sched_barrier(0);
        block_barrier();                       // all waves' tile-st loads done
        const u16* Ac = As[st & 1];
        const u16* Bc = Bs[st & 1];
#pragma unroll
        for (int ks = 0; ks < 2; ++ks) {
            bf16x8 av[FM], bv[FN];
#pragma unroll
            for (int i = 0; i < FM; ++i)
                av[i] = *(const bf16x8*)&Ac[swz(wr * (BM / 2) + i * 16 + fr, ks * 32 + fq * 8)];
#pragma unroll
            for (int j = 0; j < FN; ++j)
                bv[j] = *(const bf16x8*)&Bc[swz(wc * (BN / 2) + j * 16 + fr, ks * 32 + fq * 8)];
#pragma unroll
            for (int i = 0; i < FM; ++i)
#pragma unroll
                for (int j = 0; j < FN; ++j)
                    acc[i][j] = __builtin_amdgcn_mfma_f32_16x16x32_bf16(av[i], bv[j], acc[i][j], 0, 0, 0);
        }
        asm volatile("s_waitcnt lgkmcnt(0)" ::: "memory");  // our ds_reads retired
        __builtin_amdgcn_sched_barrier(0);
        block_barrier();                       // slot st&1 free for overwrite
        if (st + 2 < nsteps) stage(st + 2, st & 1);
    }

    if constexpr (EPI == 4) {
        // fused QKVG epilogue. BN=64 -> block covers exactly one head region.
        const int region = n0 >> 9;            // 0=Q 1=K 2=V 3=G
        const int h = (n0 & 511) >> 6;
        const int b = m0 >> 11;
        const int bh = b * NH + h;
        const int s0 = m0 & 2047;
        if (region == 3) {
#pragma unroll
            for (int i = 0; i < FM; ++i)
#pragma unroll
                for (int j = 0; j < FN; ++j)
#pragma unroll
                    for (int r = 0; r < 4; ++r) {
                        const int m = m0 + wr * (BM / 2) + i * 16 + fq * 4 + r;
                        const int e = wc * (BN / 2) + j * 16 + fr;
                        gb[(size_t)m * 512 + h * 64 + e] = f2bf(acc[i][j][r]);
                    }
        } else if (region <= 1) {
            u16* dst = (region == 0) ? qb : kb;
#pragma unroll
            for (int i = 0; i < FM; ++i)
#pragma unroll
                for (int j = 0; j < FN; ++j)
#pragma unroll
                    for (int r = 0; r < 4; ++r) {
                        const int s = s0 + wr * (BM / 2) + i * 16 + fq * 4 + r;
                        const int e = wc * (BN / 2) + j * 16 + fr;
                        const float v = acc[i][j][r];
                        const float p = __shfl_xor(v, 1, 64);
                        const float rot = (e & 1) ? p : -p;
                        const float4 t4 = tab4[(size_t)s * 32 + (e >> 1)];
                        const float scl = (region == 0) ? t4.z : t4.w;
                        dst[((size_t)bh * 2048 + s) * 64 + e] =
                            f2bf((v * t4.y + rot * t4.x) * scl);
                    }
        } else {
            // V: transpose (s,e)->(e,s) through LDS, coalesced write to Vt
            constexpr int LTS = BM + 8;
            u16* LT = (u16*)As;                // 64 x LTS u16 (fits in As)
#pragma unroll
            for (int i = 0; i < FM; ++i)
#pragma unroll
                for (int j = 0; j < FN; ++j)
#pragma unroll
                    for (int r = 0; r < 4; ++r) {
                        const int sl = wr * (BM / 2) + i * 16 + fq * 4 + r;
                        const int e = wc * (BN / 2) + j * 16 + fr;
                        LT[e * LTS + sl] = f2bf(acc[i][j][r]);
                    }
            __syncthreads();
            for (int c = t; c < 64 * (BM / 8); c += 256) {
                const int er = c / (BM / 8);
                const int sc = (c % (BM / 8)) * 8;
                const u32x4 vrow = *(const u32x4*)&LT[er * LTS + sc];
                *(u32x4*)&vt[((size_t)bh * 64 + er) * 2048 + s0 + sc] = vrow;
            }
        }
    } else {
#pragma unroll
        for (int i = 0; i < FM; ++i)
#pragma unroll
            for (int j = 0; j < FN; ++j)
#pragma unroll
                for (int r = 0; r < 4; ++r) {
                    const int m = m0 + wr * (BM / 2) + i * 16 + fq * 4 + r;
                    const int n = n0 + wc * (BN / 2) + j * 16 + fr;
                    const size_t idx = (size_t)m * N + n;
                    float v = acc[i][j][r];
                    if constexpr (EPI == 0) {
                        obf[idx] = f2bf(v);
                    } else if constexpr (EPI == 1) {
                        of32[idx] = v + res[idx];
                    } else if constexpr (EPI == 2) {
                        float tt = v + bias[n];
                        obf[idx] = f2bf(0.5f * tt * (1.f + erff(tt * 0.7071067811865475f)));
                    } else {
                        of32[idx] = v + bias[n] + res[idx];
                    }
                }
    }
}

// ---------------- fused retention + groupnorm + silu gate ----------------
// 8 waves, KVBLK=128, double-buffered global_load_lds staging, 2 barriers/iter,
// factored decay mask, decay-window truncation, XCD-chunked bh mapping.
__global__ __launch_bounds__(512)
void retention(const u16* __restrict__ Qb, const u16* __restrict__ Kb,
               const u16* __restrict__ Vt, const u16* __restrict__ gate,
               const float* __restrict__ gnw, const float* __restrict__ gnb,
               u16* __restrict__ zb) {
    extern __shared__ __align__(16) char smem[];
    u16* KsB = (u16*)smem;                 // [2][128*64]  32KB
    u16* VsB = (u16*)(smem + 32768);       // [2][64*128]  32KB
    u16* Qs  = (u16*)(smem + 65536);       // [64*64]       8KB
    u16* Ps  = (u16*)(smem + 73728);       // [64*128]     16KB

    // XCD chunking: each XCD owns 2 whole (b,h) pairs -> K/V L2-resident
    const int logical = (blockIdx.x & 7) * 64 + (blockIdx.x >> 3);
    const int bh = logical >> 5;
    const int qt = 31 - (logical & 31);    // LPT: long blocks first
    const int h = bh & 7, b = bh >> 3;
    const int t = threadIdx.x;
    const int lane = t & 63, w = t >> 6;
    const int fr = lane & 15, fq = lane >> 4;
    const int wr = w & 1, wc2 = w >> 1;    // QK: S quadrant (wr, wc2) of 64x128
    const int oc = wc2 & 1, th = w >> 2;   // PV: O quadrant (wr, oc), t-half th

    const float gamma = 1.f - expf(-3.4657359f + (float)h * -0.39608410f);
    const float lgam = log2f(gamma);
    const float dlim = 19.931568f / (-lgam);       // gamma^d < 1e-6 beyond
    const int jt_last = (qt * 64 + 63) >> 7;
    int jt_min = 0;
    {
        const float need = (float)(qt * 64 - 127) - dlim;
        if (need > 0.f) jt_min = (int)ceilf(need * (1.f / 128.f));
        if (jt_min > jt_last) jt_min = jt_last;
        if (jt_min < 0) jt_min = 0;
    }

    float rowf[2][4], colf[2];
#pragma unroll
    for (int i = 0; i < 2; ++i)
#pragma unroll
        for (int rr = 0; rr < 4; ++rr)
            rowf[i][rr] = exp2f((float)(wr * 32 + i * 16 + fq * 4 + rr) * lgam);
#pragma unroll
    for (int j = 0; j < 2; ++j)
        colf[j] = exp2f(-(float)(wc2 * 32 + j * 16 + fr) * lgam);

    const size_t bh2048 = (size_t)bh * 2048;
    const int lr8 = lane >> 3, ls8 = lane & 7;
    const int lr16 = lane >> 4, ls16 = lane & 15;

    // stage Q once (64 rows x 128B)
    {
        const int row = w * 8 + lr8;
        const int cc = ls8 ^ (row & 7);
        gload16(&Qb[(bh2048 + qt * 64 + row) * 64 + cc * 8], &Qs[w * 512]);
    }

    f32x4 oacc[2][2] = {};
    int cur = 0;
    // prologue stage
    {
        const int jt = jt_min;
        u16* Kd = KsB; u16* Vd = VsB;
#pragma unroll
        for (int q = 0; q < 2; ++q) {
            const int row = q * 64 + w * 8 + lr8;
            const int cc = ls8 ^ (row & 7);
            gload16(&Kb[(bh2048 + jt * 128 + row) * 64 + cc * 8], &Kd[(q * 64 + w * 8) * 64]);
        }
#pragma unroll
        for (int q = 0; q < 2; ++q) {
            const int row = w * 8 + q * 4 + lr16;
            const int cc = ls16 ^ (row & 15);
            gload16(&Vt[((size_t)bh * 64 + row) * 2048 + jt * 128 + cc * 8], &Vd[(w * 8 + q * 4) * 128]);
        }
    }

    for (int jt = jt_min; jt <= jt_last; ++jt) {
        __syncthreads();                       // buf[cur] staged; P consumed
        if (jt < jt_last) {                    // prefetch next tile into buf[cur^1]
            const int nb = cur ^ 1;
            u16* Kd = KsB + nb * 8192;
            u16* Vd = VsB + nb * 8192;
#pragma unroll
            for (int q = 0; q < 2; ++q) {
                const int row = q * 64 + w * 8 + lr8;
                const int cc = ls8 ^ (row & 7);
                gload16(&Kb[(bh2048 + (jt + 1) * 128 + row) * 64 + cc * 8], &Kd[(q * 64 + w * 8) * 64]);
            }
#pragma unroll
            for (int q = 0; q < 2; ++q) {
                const int row = w * 8 + q * 4 + lr16;
                const int cc = ls16 ^ (row & 15);
                gload16(&Vt[((size_t)bh * 64 + row) * 2048 + (jt + 1) * 128 + cc * 8], &Vd[(w * 8 + q * 4) * 128]);
            }
        }
        const u16* Kc = KsB + cur * 8192;
        f32x4 sac[2][2] = {};
#pragma unroll
        for (int ks = 0; ks < 2; ++ks) {
            bf16x8 qa[2], kb2[2];
#pragma unroll
            for (int i = 0; i < 2; ++i)
                qa[i] = *(const bf16x8*)&Qs[swz(wr * 32 + i * 16 + fr, ks * 32 + fq * 8)];
#pragma unroll
            for (int j = 0; j < 2; ++j)
                kb2[j] = *(const bf16x8*)&Kc[swz(wc2 * 32 + j * 16 + fr, ks * 32 + fq * 8)];
#pragma unroll
            for (int i = 0; i < 2; ++i)
#pragma unroll
                for (int j = 0; j < 2; ++j)
                    sac[i][j] = __builtin_amdgcn_mfma_f32_16x16x32_bf16(qa[i], kb2[j], sac[i][j], 0, 0, 0);
        }
        const float sc = exp2f((float)(qt * 64 - jt * 128) * lgam);
        const bool diag = (jt == jt_last);
#pragma unroll
        for (int i = 0; i < 2; ++i)
#pragma unroll
            for (int j = 0; j < 2; ++j)
#pragma unroll
                for (int rr = 0; rr < 4; ++rr) {
                    float m = sc * rowf[i][rr] * colf[j];
                    if (diag) {
                        const int d = (qt * 64 + wr * 32 + i * 16 + fq * 4 + rr)
                                    - (jt * 128 + wc2 * 32 + j * 16 + fr);
                        if (d < 0) m = 0.f;
                    }
                    Ps[swzP(wr * 32 + i * 16 + fq * 4 + rr, wc2 * 32 + j * 16 + fr)] =
                        f2bf(sac[i][j][rr] * m);
                }
        __syncthreads();                       // P visible
        const u16* Vc = VsB + cur * 8192;
#pragma unroll
        for (int ks = 0; ks < 2; ++ks) {
            const int tcol = th * 64 + ks * 32 + fq * 8;
            bf16x8 pa[2], vb[2];
#pragma unroll
            for (int i = 0; i < 2; ++i)
                pa[i] = *(const bf16x8*)&Ps[swzP(wr * 32 + i * 16 + fr, tcol)];
#pragma unroll
            for (int j = 0; j < 2; ++j)
                vb[j] = *(const bf16x8*)&Vc[swzP(oc * 32 + j * 16 + fr, tcol)];
#pragma unroll
            for (int i = 0; i < 2; ++i)
#pragma unroll
                for (int j = 0; j < 2; ++j)
                    oacc[i][j] = __builtin_amdgcn_mfma_f32_16x16x32_bf16(pa[i], vb[j], oacc[i][j], 0, 0, 0);
        }
        cur ^= 1;
    }

    // ---- cross-t-half reduce + groupnorm + gate ----
    __syncthreads();
    float* Of = (float*)smem;                 // [64][66] f32, aliases K buffers
    if (th == 1) {
#pragma unroll
        for (int i = 0; i < 2; ++i)
#pragma unroll
            for (int j = 0; j < 2; ++j)
#pragma unroll
                for (int rr = 0; rr < 4; ++rr)
                    Of[(wr * 32 + i * 16 + fq * 4 + rr) * 66 + oc * 32 + j * 16 + fr] = oacc[i][j][rr];
    }
    __syncthreads();
    if (th == 0) {
#pragma unroll
        for (int i = 0; i < 2; ++i)
#pragma unroll
            for (int j = 0; j < 2; ++j)
#pragma unroll
                for (int rr = 0; rr < 4; ++rr) {
                    const int idx = (wr * 32 + i * 16 + fq * 4 + rr) * 66 + oc * 32 + j * 16 + fr;
                    Of[idx] += oacc[i][j][rr];
                }
    }
    __syncthreads();
    const int row = t >> 3, c0 = (t & 7) * 8;
    float v[8];
    float s = 0.f, s2 = 0.f;
#pragma unroll
    for (int i = 0; i < 8; ++i) {
        v[i] = Of[row * 66 + c0 + i];
        s += v[i]; s2 += v[i] * v[i];
    }
    s  += __shfl_xor(s, 1, 64);  s  += __shfl_xor(s, 2, 64);  s  += __shfl_xor(s, 4, 64);
    s2 += __shfl_xor(s2, 1, 64); s2 += __shfl_xor(s2, 2, 64); s2 += __shfl_xor(s2, 4, 64);
    const float mu = s * (1.f / 64.f);
    const float rs = rsqrtf(s2 * (1.f / 64.f) - mu * mu + 1e-5f);
    const int sg = qt * 64 + row;
    u16 gv[8] __attribute__((aligned(16)));
    *(u32x4*)gv = *(const u32x4*)&gate[((size_t)(b * SSL + sg)) * 512 + h * 64 + c0];
    u16 ob[8] __attribute__((aligned(16)));
#pragma unroll
    for (int i = 0; i < 8; ++i) {
        const int dc = h * 64 + c0 + i;
        const float yn = (v[i] - mu) * rs * gnw[dc] + gnb[dc];
        const float g = bf2f(gv[i]);
        ob[i] = f2bf(yn * (g / (1.f + expf(-g))));
    }
    *(u32x4*)&zb[((size_t)(b * SSL + sg)) * 512 + h * 64 + c0] = *(const u32x4*)ob;
}

// ---------------- host ----------------
extern "C" void kernel_launch(void* const* d_in, const int* in_sizes, int n_in,
                              void* d_out, int out_size, void* d_ws, size_t ws_size,
                              hipStream_t stream) {
    const float* X    = (const float*)d_in[0];
    const float* WQ   = (const float*)d_in[1];
    const float* WK   = (const float*)d_in[2];
    const float* WV   = (const float*)d_in[3];
    const float* WG   = (const float*)d_in[4];
    const float* WO   = (const float*)d_in[5];
    const float* GNW  = (const float*)d_in[6];
    const float* GNB  = (const float*)d_in[7];
    const float* LN1W = (const float*)d_in[8];
    const float* LN1B = (const float*)d_in[9];
    const float* LN2W = (const float*)d_in[10];
    const float* LN2B = (const float*)d_in[11];
    const float* FW1  = (const float*)d_in[12];
    const float* FB1  = (const float*)d_in[13];
    const float* FW2  = (const float*)d_in[14];
    const float* FB2  = (const float*)d_in[15];

    char* ws = (char*)d_ws;
    size_t off = 0;
    auto alloc = [&](size_t n) { char* p = ws + off; off += (n + 255) & ~(size_t)255; return p; };

    u16*   WBT  = (u16*)alloc((size_t)LYR * 2048 * 512 * 2);
    u16*   WOT  = (u16*)alloc((size_t)LYR * 512 * 512 * 2);
    u16*   W1T  = (u16*)alloc((size_t)LYR * 2048 * 512 * 2);
    u16*   W2T  = (u16*)alloc((size_t)LYR * 512 * 2048 * 2);
    float4* TAB4 = (float4*)alloc((size_t)2048 * 32 * 16);
    float* XB   = (float*)alloc((size_t)NROWS * DM * 4);
    u16*   XN   = (u16*)alloc((size_t)NROWS * DM * 2);
    u16*   FF1  = (u16*)alloc((size_t)NROWS * 2048 * 2);
    u16*   GB   = (u16*)alloc((size_t)NROWS * DM * 2);
    u16*   QBp  = (u16*)alloc((size_t)NROWS * DM * 2);
    u16*   KBp  = (u16*)alloc((size_t)NROWS * DM * 2);
    u16*   VTp  = (u16*)alloc((size_t)NROWS * DM * 2);
    u16*   ZB   = (u16*)alloc((size_t)NROWS * DM * 2);
    float* Y1   = (float*)alloc((size_t)NROWS * DM * 4);
    u16*   HB   = QBp;   // alias: QB dead after retention

    xpos_tables<<<256, 256, 0, stream>>>(TAB4);
    prep_qkv<<<dim3(8, 24, LYR), 256, 0, stream>>>(WQ, WK, WV, WBT);
    prep_t<<<dim3(8, 8, LYR), 256, 0, stream>>>(WG, WBT + 1536 * 512, 512, 512,
                                                (long long)512 * 512, (long long)2048 * 512);
    prep_t<<<dim3(8, 8, LYR), 256, 0, stream>>>(WO, WOT, 512, 512,
                                                (long long)512 * 512, (long long)512 * 512);
    prep_t<<<dim3(8, 32, LYR), 256, 0, stream>>>(FW1, W1T, 512, 2048,
                                                 (long long)512 * 2048, (long long)2048 * 512);
    prep_t<<<dim3(32, 8, LYR), 256, 0, stream>>>(FW2, W2T, 2048, 512,
                                                 (long long)2048 * 512, (long long)512 * 2048);

    for (int l = 0; l < LYR; ++l) {
        const float* xsrc = (l == 0) ? X : XB;
        float* xdst = (l == LYR - 1) ? (float*)d_out : XB;
        ln_kernel<<<NROWS / 4, 256, 0, stream>>>(xsrc, LN1W + l * 512, LN1B + l * 512, XN);
        gemm_bt<128, 64, 4><<<1024, 256, 0, stream>>>(
            XN, WBT + (size_t)l * 2048 * 512, nullptr, nullptr, nullptr, nullptr,
            QBp, KBp, VTp, GB, TAB4, NROWS, 2048, 512);
        retention<<<512, 512, 90112, stream>>>(QBp, KBp, VTp, GB,
                                               GNW + l * 512, GNB + l * 512, ZB);
        gemm_bt<64, 128, 1><<<256, 256, 0, stream>>>(
            ZB, WOT + (size_t)l * 512 * 512, nullptr, Y1, xsrc, nullptr,
            nullptr, nullptr, nullptr, nullptr, nullptr, NROWS, 512, 512);
        ln_kernel<<<NROWS / 4, 256, 0, stream>>>(Y1, LN2W + l * 512, LN2B + l * 512, HB);
        gemm_bt<128, 64, 2><<<1024, 256, 0, stream>>>(
            HB, W1T + (size_t)l * 2048 * 512, FF1, nullptr, nullptr, FB1 + l * 2048,
            nullptr, nullptr, nullptr, nullptr, nullptr, NROWS, 2048, 512);
        gemm_bt<64, 128, 3><<<256, 256, 0, stream>>>(
            FF1, W2T + (size_t)l * 512 * 2048, nullptr, xdst, Y1, FB2 + l * 512,
            nullptr, nullptr, nullptr, nullptr, nullptr, NROWS, 512, 2048);
    }
}

// Round 6
// 455.342 us; speedup vs baseline: 1.1762x; 1.0482x over previous
//
#include <hip/hip_runtime.h>
#include <hip/hip_bf16.h>

#define LYR 4
#define NH  8
#define DM  512
#define DHD 64
#define DFF 2048
#define BB  2
#define SSL 2048
#define NROWS (BB*SSL)   // 4096

typedef unsigned short u16;
typedef __attribute__((ext_vector_type(8))) short bf16x8;
typedef __attribute__((ext_vector_type(4))) float f32x4;
typedef __attribute__((ext_vector_type(4))) unsigned int u32x4;

__device__ __forceinline__ u16 f2bf(float f) {
    union { float f; unsigned u; } v; v.f = f;
    unsigned r = v.u + 0x7FFFu + ((v.u >> 16) & 1u);
    return (u16)(r >> 16);
}
__device__ __forceinline__ float bf2f(u16 b) {
    union { unsigned u; float f; } v; v.u = ((unsigned)b) << 16;
    return v.f;
}
// XOR-swizzled LDS index for [*][64]-u16 (128B-row) tiles, 16B granules.
__device__ __forceinline__ int swz(int row, int col) {
    return row * 64 + (col & 7) + ((((col >> 3) ^ row) & 7) << 3);
}
// same for [*][128]-u16 (256B-row) tiles, 16 slots
__device__ __forceinline__ int swzP(int row, int col) {
    return row * 128 + (col & 7) + ((((col >> 3) ^ row) & 15) << 3);
}
// async global->LDS, 16B per lane; LDS dest = wave-uniform base + lane*16
__device__ __forceinline__ void gload16(const u16* g, u16* l) {
    __builtin_amdgcn_global_load_lds(
        (const __attribute__((address_space(1))) unsigned int*)g,
        (__attribute__((address_space(3))) unsigned int*)l, 16, 0, 0);
}
template <int N> __device__ __forceinline__ void wait_vmcnt() {
    if constexpr (N == 0)      asm volatile("s_waitcnt vmcnt(0)" ::: "memory");
    else if constexpr (N == 6) asm volatile("s_waitcnt vmcnt(6)" ::: "memory");
    else static_assert(N == 0 || N == 6, "unsupported vmcnt");
}
__device__ __forceinline__ void block_barrier() {
    __builtin_amdgcn_s_barrier();
    asm volatile("" ::: "memory");
}

// ---------------- precompute kernels ----------------

// packed per-(s, jpair) xPos table: {sin, cos, scale_q, scale_k}
__global__ __launch_bounds__(256) void xpos_tables(float4* __restrict__ tab4) {
    const int idx = blockIdx.x * 256 + threadIdx.x;  // 2048*32
    const int s = idx >> 5, j = idx & 31;
    const float base = (2.f * j + 0.4f * 64.f) / (1.4f * 64.f);
    const float invf = powf(10000.f, -(float)j / 32.f);
    const float ang = (float)s * invf;
    const float scq = powf(base, (float)s / 512.f);
    tab4[idx] = make_float4(sinf(ang), cosf(ang), scq, 1.f / scq);
}

// WQ/WK/WV (l,h,512,64) f32 -> WBT[l] rows (which*512 + h*64 + e), cols d (bf16, Bt layout)
__global__ __launch_bounds__(256)
void prep_qkv(const float* __restrict__ WQp, const float* __restrict__ WKp,
              const float* __restrict__ WVp, u16* __restrict__ WBT) {
    const int dt = blockIdx.x;                       // 0..7 d-tile
    const int h = blockIdx.y & 7, which = blockIdx.y >> 3;
    const int l = blockIdx.z;
    const float* W = (which == 0 ? WQp : which == 1 ? WKp : WVp);
    const float* ip = W + ((size_t)(l * 8 + h)) * (512 * 64);
    u16* op = WBT + (size_t)l * (2048 * 512) + (size_t)(which * 512 + h * 64) * 512;
    __shared__ u16 tile[64 * 72];
    const int t = threadIdx.x, rr = t >> 2, cc = (t & 3) * 16;
    const float* src = ip + (size_t)(dt * 64 + rr) * 64 + cc;
#pragma unroll
    for (int i = 0; i < 16; ++i) tile[rr * 72 + cc + i] = f2bf(src[i]);
    __syncthreads();
    u16 tmp[16] __attribute__((aligned(16)));
#pragma unroll
    for (int i = 0; i < 16; ++i) tmp[i] = tile[(cc + i) * 72 + rr];
    u16* dst = op + (size_t)rr * 512 + dt * 64 + cc;
    *(u32x4*)&dst[0] = *(const u32x4*)&tmp[0];
    *(u32x4*)&dst[8] = *(const u32x4*)&tmp[8];
}

// generic f32 (R,C) row-major -> bf16 out (C,R) row-major, per-layer z
__global__ __launch_bounds__(256)
void prep_t(const float* __restrict__ in, u16* __restrict__ out, int R, int C,
            long long in_ls, long long out_ls) {
    const float* ip = in + (size_t)blockIdx.z * in_ls;
    u16* op = out + (size_t)blockIdx.z * out_ls;
    const int r0 = blockIdx.x * 64, c0t = blockIdx.y * 64;
    __shared__ u16 tile[64 * 72];
    const int t = threadIdx.x, rr = t >> 2, cc = (t & 3) * 16;
    const float* src = ip + (size_t)(r0 + rr) * C + c0t + cc;
#pragma unroll
    for (int i = 0; i < 16; ++i) tile[rr * 72 + cc + i] = f2bf(src[i]);
    __syncthreads();
    u16 tmp[16] __attribute__((aligned(16)));
#pragma unroll
    for (int i = 0; i < 16; ++i) tmp[i] = tile[(cc + i) * 72 + rr];
    u16* dst = op + (size_t)(c0t + rr) * R + r0 + cc;
    *(u32x4*)&dst[0] = *(const u32x4*)&tmp[0];
    *(u32x4*)&dst[8] = *(const u32x4*)&tmp[8];
}

// ---------------- LayerNorm (one wave per 512-wide row) ----------------
__global__ __launch_bounds__(256)
void ln_kernel(const float* __restrict__ x, const float* __restrict__ wt,
               const float* __restrict__ bs, u16* __restrict__ out) {
    const int row = blockIdx.x * 4 + (threadIdx.x >> 6);
    const int lane = threadIdx.x & 63;
    const float* xr = x + (size_t)row * DM + lane * 8;
    float v[8];
    *(float4*)&v[0] = *(const float4*)&xr[0];
    *(float4*)&v[4] = *(const float4*)&xr[4];
    float s = 0.f, s2 = 0.f;
#pragma unroll
    for (int i = 0; i < 8; ++i) { s += v[i]; s2 += v[i] * v[i]; }
#pragma unroll
    for (int m = 1; m < 64; m <<= 1) {
        s  += __shfl_xor(s, m, 64);
        s2 += __shfl_xor(s2, m, 64);
    }
    const float mu = s * (1.f / DM);
    const float rs = rsqrtf(s2 * (1.f / DM) - mu * mu + 1e-5f);
    const int e0 = lane * 8;
    u16 o[8] __attribute__((aligned(16)));
#pragma unroll
    for (int i = 0; i < 8; ++i)
        o[i] = f2bf((v[i] - mu) * rs * wt[e0 + i] + bs[e0 + i]);
    *(u32x4*)&out[(size_t)row * DM + e0] = *(const u32x4*)o;
}

// ---------------- small bf16 GEMM (256 thr): C = A * Bt^T ----------------
// round-3 skeleton: global_load_lds double-buffer, counted vmcnt(6),
// raw s_barrier, XCD-chunked block mapping.
// EPI 1: f32 acc+res | 3: f32 acc+bias+res
template <int BM, int BN, int EPI>
__global__ __launch_bounds__(256)
void gemm_bt(const u16* __restrict__ A, const u16* __restrict__ Bt,
             u16* __restrict__ obf, float* __restrict__ of32,
             const float* __restrict__ res, const float* __restrict__ bias,
             int M, int N, int K) {
    constexpr int FM = BM / 32, FN = BN / 32;
    constexpr int LPS = BM / 32 + BN / 32;
    static_assert(LPS == 6, "vmcnt template expects 6");
    __shared__ __align__(16) u16 As[2][BM * 64];
    __shared__ __align__(16) u16 Bs[2][BN * 64];
    const int t = threadIdx.x;
    const int lane = t & 63, w4 = t >> 6;
    const int wr = w4 >> 1, wc = w4 & 1;
    const int fr = lane & 15, fq = lane >> 4;
    const int nX = N / BN;
    const int nwg = (M / BM) * nX;
    const int swzid = (blockIdx.x & 7) * (nwg >> 3) + (blockIdx.x >> 3);
    const int m0 = (swzid / nX) * BM, n0 = (swzid % nX) * BN;
    const int lr = lane >> 3;
    const int ls = lane & 7;
    const int nsteps = K >> 6;

    auto stage = [&](int step, int slot) {
        const int k0 = step << 6;
#pragma unroll
        for (int q = 0; q < BM / 32; ++q) {
            const int ib = q * 4 + w4;
            const int row = ib * 8 + lr;
            const int cc = ls ^ (row & 7);
            gload16(&A[(size_t)(m0 + row) * K + k0 + cc * 8], &As[slot][ib * 512]);
        }
#pragma unroll
        for (int q = 0; q < BN / 32; ++q) {
            const int ib = q * 4 + w4;
            const int row = ib * 8 + lr;
            const int cc = ls ^ (row & 7);
            gload16(&Bt[(size_t)(n0 + row) * K + k0 + cc * 8], &Bs[slot][ib * 512]);
        }
    };

    f32x4 acc[FM][FN] = {};
    stage(0, 0);
    stage(1, 1);
    for (int st = 0; st < nsteps; ++st) {
        if (st + 1 < nsteps) wait_vmcnt<LPS>(); else wait_vmcnt<0>();
        __builtin_amdgcn_sched_barrier(0);
        block_barrier();
        const u16* Ac = As[st & 1];
        const u16* Bc = Bs[st & 1];
#pragma unroll
        for (int ks = 0; ks < 2; ++ks) {
            bf16x8 av[FM], bv[FN];
#pragma unroll
            for (int i = 0; i < FM; ++i)
                av[i] = *(const bf16x8*)&Ac[swz(wr * (BM / 2) + i * 16 + fr, ks * 32 + fq * 8)];
#pragma unroll
            for (int j = 0; j < FN; ++j)
                bv[j] = *(const bf16x8*)&Bc[swz(wc * (BN / 2) + j * 16 + fr, ks * 32 + fq * 8)];
#pragma unroll
            for (int i = 0; i < FM; ++i)
#pragma unroll
                for (int j = 0; j < FN; ++j)
                    acc[i][j] = __builtin_amdgcn_mfma_f32_16x16x32_bf16(av[i], bv[j], acc[i][j], 0, 0, 0);
        }
        asm volatile("s_waitcnt lgkmcnt(0)" ::: "memory");
        __builtin_amdgcn_sched_barrier(0);
        block_barrier();
        if (st + 2 < nsteps) stage(st + 2, st & 1);
    }
#pragma unroll
    for (int i = 0; i < FM; ++i)
#pragma unroll
        for (int j = 0; j < FN; ++j)
#pragma unroll
            for (int r = 0; r < 4; ++r) {
                const int m = m0 + wr * (BM / 2) + i * 16 + fq * 4 + r;
                const int n = n0 + wc * (BN / 2) + j * 16 + fr;
                const size_t idx = (size_t)m * N + n;
                float v = acc[i][j][r];
                if constexpr (EPI == 1) {
                    of32[idx] = v + res[idx];
                } else {
                    of32[idx] = v + bias[n] + res[idx];
                }
            }
}

// ---------------- big bf16 GEMM (512 thr, 256x128): C = A * Bt^T ----------------
// same proven sync skeleton; 8 waves (2m x 4n), wave tile 128x32.
// 48KB staged bytes/K-step per CU -> compute-bound (vs 64KB at 128^2 x2/CU).
// EPI 2: bf16 = gelu(acc+bias) | EPI 4: fused QKVG epilogue
template <int EPI>
__global__ __launch_bounds__(512, 1)
void gemm_big(const u16* __restrict__ A, const u16* __restrict__ Bt,
              u16* __restrict__ obf, const float* __restrict__ bias,
              u16* __restrict__ qb, u16* __restrict__ kb, u16* __restrict__ vt,
              u16* __restrict__ gb, const float4* __restrict__ tab4,
              int M, int N, int K) {
    constexpr int BM = 256, BN = 128;
    __shared__ __align__(16) u16 SM[49152];          // 96KB: A 2x16384, B 2x8192
    const int t = threadIdx.x;
    const int lane = t & 63, w = t >> 6;
    const int wr = w >> 2, wcn = w & 3;              // 2 m-halves x 4 n-quarters
    const int fr = lane & 15, fq = lane >> 4;
    const int nX = N / BN;
    const int nwg = (M / BM) * nX;
    const int swzid = (blockIdx.x & 7) * (nwg >> 3) + (blockIdx.x >> 3);
    const int m0 = (swzid / nX) * BM, n0 = (swzid % nX) * BN;
    const int lr = lane >> 3, ls = lane & 7;
    const int nsteps = K >> 6;

    auto stage = [&](int step, int slot) {
        const int k0 = step << 6;
#pragma unroll
        for (int q = 0; q < 4; ++q) {                // A: 256 rows
            const int ib = q * 8 + w;
            const int row = ib * 8 + lr;
            const int cc = ls ^ (row & 7);
            gload16(&A[(size_t)(m0 + row) * K + k0 + cc * 8], &SM[slot * 16384 + ib * 512]);
        }
#pragma unroll
        for (int q = 0; q < 2; ++q) {                // B: 128 rows
            const int ib = q * 8 + w;
            const int row = ib * 8 + lr;
            const int cc = ls ^ (row & 7);
            gload16(&Bt[(size_t)(n0 + row) * K + k0 + cc * 8],
                    &SM[32768 + slot * 8192 + ib * 512]);
        }
    };

    f32x4 acc[8][2] = {};
    stage(0, 0);
    stage(1, 1);
    for (int st = 0; st < nsteps; ++st) {
        if (st + 1 < nsteps) wait_vmcnt<6>(); else wait_vmcnt<0>();
        __builtin_amdgcn_sched_barrier(0);
        block_barrier();
        const u16* Ac = &SM[(st & 1) * 16384];
        const u16* Bc = &SM[32768 + (st & 1) * 8192];
#pragma unroll
        for (int ks = 0; ks < 2; ++ks) {
            bf16x8 bv[2];
#pragma unroll
            for (int j = 0; j < 2; ++j)
                bv[j] = *(const bf16x8*)&Bc[swz(wcn * 32 + j * 16 + fr, ks * 32 + fq * 8)];
            __builtin_amdgcn_s_setprio(1);
#pragma unroll
            for (int i = 0; i < 8; ++i) {
                bf16x8 av = *(const bf16x8*)&Ac[swz(wr * 128 + i * 16 + fr, ks * 32 + fq * 8)];
                acc[i][0] = __builtin_amdgcn_mfma_f32_16x16x32_bf16(av, bv[0], acc[i][0], 0, 0, 0);
                acc[i][1] = __builtin_amdgcn_mfma_f32_16x16x32_bf16(av, bv[1], acc[i][1], 0, 0, 0);
            }
            __builtin_amdgcn_s_setprio(0);
        }
        asm volatile("s_waitcnt lgkmcnt(0)" ::: "memory");
        __builtin_amdgcn_sched_barrier(0);
        block_barrier();
        if (st + 2 < nsteps) stage(st + 2, st & 1);
    }

    if constexpr (EPI == 2) {
#pragma unroll
        for (int i = 0; i < 8; ++i)
#pragma unroll
            for (int j = 0; j < 2; ++j)
#pragma unroll
                for (int r = 0; r < 4; ++r) {
                    const int m = m0 + wr * 128 + i * 16 + fq * 4 + r;
                    const int n = n0 + wcn * 32 + j * 16 + fr;
                    float tt = acc[i][j][r] + bias[n];
                    obf[(size_t)m * N + n] = f2bf(0.5f * tt * (1.f + erff(tt * 0.7071067811865475f)));
                }
    } else {
        // fused QKVG epilogue; BN=128 spans 2 heads within one region.
        const int region = n0 >> 9;            // 0=Q 1=K 2=V 3=G
        const int h = (n0 & 511) >> 6;
        const int b = m0 >> 11;
        const int s0 = m0 & 2047;
        if (region == 3) {
#pragma unroll
            for (int i = 0; i < 8; ++i)
#pragma unroll
                for (int j = 0; j < 2; ++j)
#pragma unroll
                    for (int r = 0; r < 4; ++r) {
                        const int m = m0 + wr * 128 + i * 16 + fq * 4 + r;
                        const int el = wcn * 32 + j * 16 + fr;
                        gb[(size_t)m * 512 + (n0 & 511) + el] = f2bf(acc[i][j][r]);
                    }
        } else if (region <= 1) {
            u16* dst = (region == 0) ? qb : kb;
#pragma unroll
            for (int i = 0; i < 8; ++i)
#pragma unroll
                for (int j = 0; j < 2; ++j)
#pragma unroll
                    for (int r = 0; r < 4; ++r) {
                        const int s = s0 + wr * 128 + i * 16 + fq * 4 + r;
                        const int el = wcn * 32 + j * 16 + fr;
                        const int hh = h + (el >> 6), e = el & 63;
                        const float v = acc[i][j][r];
                        const float p = __shfl_xor(v, 1, 64);
                        const float rot = (e & 1) ? p : -p;
                        const float4 t4 = tab4[(size_t)s * 32 + (e >> 1)];
                        const float scl = (region == 0) ? t4.z : t4.w;
                        dst[((size_t)(b * NH + hh) * 2048 + s) * 64 + e] =
                            f2bf((v * t4.y + rot * t4.x) * scl);
                    }
        } else {
            // V: transpose (s,e)->(e,s) through LDS, coalesced write to Vt
            u16* LT = SM;                      // 128 x 264 u16 (67.5KB < 96KB)
#pragma unroll
            for (int i = 0; i < 8; ++i)
#pragma unroll
                for (int j = 0; j < 2; ++j)
#pragma unroll
                    for (int r = 0; r < 4; ++r) {
                        const int sl = wr * 128 + i * 16 + fq * 4 + r;
                        const int el = wcn * 32 + j * 16 + fr;
                        LT[el * 264 + sl] = f2bf(acc[i][j][r]);
                    }
            __syncthreads();
            for (int c = t; c < 128 * 32; c += 512) {
                const int er = c >> 5;
                const int sc = (c & 31) * 8;
                const int hh = h + (er >> 6), e = er & 63;
                *(u32x4*)&vt[((size_t)(b * NH + hh) * 64 + e) * 2048 + s0 + sc] =
                    *(const u32x4*)&LT[er * 264 + sc];
            }
        }
    }
}

// ---------------- fused retention + groupnorm + silu gate ----------------
__global__ __launch_bounds__(512)
void retention(const u16* __restrict__ Qb, const u16* __restrict__ Kb,
               const u16* __restrict__ Vt, const u16* __restrict__ gate,
               const float* __restrict__ gnw, const float* __restrict__ gnb,
               u16* __restrict__ zb) {
    extern __shared__ __align__(16) char smem[];
    u16* KsB = (u16*)smem;                 // [2][128*64]  32KB
    u16* VsB = (u16*)(smem + 32768);       // [2][64*128]  32KB
    u16* Qs  = (u16*)(smem + 65536);       // [64*64]       8KB
    u16* Ps  = (u16*)(smem + 73728);       // [64*128]     16KB

    const int logical = (blockIdx.x & 7) * 64 + (blockIdx.x >> 3);
    const int bh = logical >> 5;
    const int qt = 31 - (logical & 31);    // LPT: long blocks first
    const int h = bh & 7, b = bh >> 3;
    const int t = threadIdx.x;
    const int lane = t & 63, w = t >> 6;
    const int fr = lane & 15, fq = lane >> 4;
    const int wr = w & 1, wc2 = w >> 1;
    const int oc = wc2 & 1, th = w >> 2;

    const float gamma = 1.f - expf(-3.4657359f + (float)h * -0.39608410f);
    const float lgam = log2f(gamma);
    const float dlim = 19.931568f / (-lgam);
    const int jt_last = (qt * 64 + 63) >> 7;
    int jt_min = 0;
    {
        const float need = (float)(qt * 64 - 127) - dlim;
        if (need > 0.f) jt_min = (int)ceilf(need * (1.f / 128.f));
        if (jt_min > jt_last) jt_min = jt_last;
        if (jt_min < 0) jt_min = 0;
    }

    float rowf[2][4], colf[2];
#pragma unroll
    for (int i = 0; i < 2; ++i)
#pragma unroll
        for (int rr = 0; rr < 4; ++rr)
            rowf[i][rr] = exp2f((float)(wr * 32 + i * 16 + fq * 4 + rr) * lgam);
#pragma unroll
    for (int j = 0; j < 2; ++j)
        colf[j] = exp2f(-(float)(wc2 * 32 + j * 16 + fr) * lgam);

    const size_t bh2048 = (size_t)bh * 2048;
    const int lr8 = lane >> 3, ls8 = lane & 7;
    const int lr16 = lane >> 4, ls16 = lane & 15;

    {
        const int row = w * 8 + lr8;
        const int cc = ls8 ^ (row & 7);
        gload16(&Qb[(bh2048 + qt * 64 + row) * 64 + cc * 8], &Qs[w * 512]);
    }

    f32x4 oacc[2][2] = {};
    int cur = 0;
    {
        const int jt = jt_min;
        u16* Kd = KsB; u16* Vd = VsB;
#pragma unroll
        for (int q = 0; q < 2; ++q) {
            const int row = q * 64 + w * 8 + lr8;
            const int cc = ls8 ^ (row & 7);
            gload16(&Kb[(bh2048 + jt * 128 + row) * 64 + cc * 8], &Kd[(q * 64 + w * 8) * 64]);
        }
#pragma unroll
        for (int q = 0; q < 2; ++q) {
            const int row = w * 8 + q * 4 + lr16;
            const int cc = ls16 ^ (row & 15);
            gload16(&Vt[((size_t)bh * 64 + row) * 2048 + jt * 128 + cc * 8], &Vd[(w * 8 + q * 4) * 128]);
        }
    }

    for (int jt = jt_min; jt <= jt_last; ++jt) {
        __syncthreads();
        if (jt < jt_last) {
            const int nb = cur ^ 1;
            u16* Kd = KsB + nb * 8192;
            u16* Vd = VsB + nb * 8192;
#pragma unroll
            for (int q = 0; q < 2; ++q) {
                const int row = q * 64 + w * 8 + lr8;
                const int cc = ls8 ^ (row & 7);
                gload16(&Kb[(bh2048 + (jt + 1) * 128 + row) * 64 + cc * 8], &Kd[(q * 64 + w * 8) * 64]);
            }
#pragma unroll
            for (int q = 0; q < 2; ++q) {
                const int row = w * 8 + q * 4 + lr16;
                const int cc = ls16 ^ (row & 15);
                gload16(&Vt[((size_t)bh * 64 + row) * 2048 + (jt + 1) * 128 + cc * 8], &Vd[(w * 8 + q * 4) * 128]);
            }
        }
        const u16* Kc = KsB + cur * 8192;
        f32x4 sac[2][2] = {};
#pragma unroll
        for (int ks = 0; ks < 2; ++ks) {
            bf16x8 qa[2], kb2[2];
#pragma unroll
            for (int i = 0; i < 2; ++i)
                qa[i] = *(const bf16x8*)&Qs[swz(wr * 32 + i * 16 + fr, ks * 32 + fq * 8)];
#pragma unroll
            for (int j = 0; j < 2; ++j)
                kb2[j] = *(const bf16x8*)&Kc[swz(wc2 * 32 + j * 16 + fr, ks * 32 + fq * 8)];
#pragma unroll
            for (int i = 0; i < 2; ++i)
#pragma unroll
                for (int j = 0; j < 2; ++j)
                    sac[i][j] = __builtin_amdgcn_mfma_f32_16x16x32_bf16(qa[i], kb2[j], sac[i][j], 0, 0, 0);
        }
        const float sc = exp2f((float)(qt * 64 - jt * 128) * lgam);
        const bool diag = (jt == jt_last);
#pragma unroll
        for (int i = 0; i < 2; ++i)
#pragma unroll
            for (int j = 0; j < 2; ++j)
#pragma unroll
                for (int rr = 0; rr < 4; ++rr) {
                    float m = sc * rowf[i][rr] * colf[j];
                    if (diag) {
                        const int d = (qt * 64 + wr * 32 + i * 16 + fq * 4 + rr)
                                    - (jt * 128 + wc2 * 32 + j * 16 + fr);
                        if (d < 0) m = 0.f;
                    }
                    Ps[swzP(wr * 32 + i * 16 + fq * 4 + rr, wc2 * 32 + j * 16 + fr)] =
                        f2bf(sac[i][j][rr] * m);
                }
        __syncthreads();
        const u16* Vc = VsB + cur * 8192;
#pragma unroll
        for (int ks = 0; ks < 2; ++ks) {
            const int tcol = th * 64 + ks * 32 + fq * 8;
            bf16x8 pa[2], vb[2];
#pragma unroll
            for (int i = 0; i < 2; ++i)
                pa[i] = *(const bf16x8*)&Ps[swzP(wr * 32 + i * 16 + fr, tcol)];
#pragma unroll
            for (int j = 0; j < 2; ++j)
                vb[j] = *(const bf16x8*)&Vc[swzP(oc * 32 + j * 16 + fr, tcol)];
#pragma unroll
            for (int i = 0; i < 2; ++i)
#pragma unroll
                for (int j = 0; j < 2; ++j)
                    oacc[i][j] = __builtin_amdgcn_mfma_f32_16x16x32_bf16(pa[i], vb[j], oacc[i][j], 0, 0, 0);
        }
        cur ^= 1;
    }

    __syncthreads();
    float* Of = (float*)smem;                 // [64][66] f32, aliases K buffers
    if (th == 1) {
#pragma unroll
        for (int i = 0; i < 2; ++i)
#pragma unroll
            for (int j = 0; j < 2; ++j)
#pragma unroll
                for (int rr = 0; rr < 4; ++rr)
                    Of[(wr * 32 + i * 16 + fq * 4 + rr) * 66 + oc * 32 + j * 16 + fr] = oacc[i][j][rr];
    }
    __syncthreads();
    if (th == 0) {
#pragma unroll
        for (int i = 0; i < 2; ++i)
#pragma unroll
            for (int j = 0; j < 2; ++j)
#pragma unroll
                for (int rr = 0; rr < 4; ++rr) {
                    const int idx = (wr * 32 + i * 16 + fq * 4 + rr) * 66 + oc * 32 + j * 16 + fr;
                    Of[idx] += oacc[i][j][rr];
                }
    }
    __syncthreads();
    const int row = t >> 3, c0 = (t & 7) * 8;
    float v[8];
    float s = 0.f, s2 = 0.f;
#pragma unroll
    for (int i = 0; i < 8; ++i) {
        v[i] = Of[row * 66 + c0 + i];
        s += v[i]; s2 += v[i] * v[i];
    }
    s  += __shfl_xor(s, 1, 64);  s  += __shfl_xor(s, 2, 64);  s  += __shfl_xor(s, 4, 64);
    s2 += __shfl_xor(s2, 1, 64); s2 += __shfl_xor(s2, 2, 64); s2 += __shfl_xor(s2, 4, 64);
    const float mu = s * (1.f / 64.f);
    const float rs = rsqrtf(s2 * (1.f / 64.f) - mu * mu + 1e-5f);
    const int sg = qt * 64 + row;
    u16 gv[8] __attribute__((aligned(16)));
    *(u32x4*)gv = *(const u32x4*)&gate[((size_t)(b * SSL + sg)) * 512 + h * 64 + c0];
    u16 ob[8] __attribute__((aligned(16)));
#pragma unroll
    for (int i = 0; i < 8; ++i) {
        const int dc = h * 64 + c0 + i;
        const float yn = (v[i] - mu) * rs * gnw[dc] + gnb[dc];
        const float g = bf2f(gv[i]);
        ob[i] = f2bf(yn * (g / (1.f + expf(-g))));
    }
    *(u32x4*)&zb[((size_t)(b * SSL + sg)) * 512 + h * 64 + c0] = *(const u32x4*)ob;
}

// ---------------- host ----------------
extern "C" void kernel_launch(void* const* d_in, const int* in_sizes, int n_in,
                              void* d_out, int out_size, void* d_ws, size_t ws_size,
                              hipStream_t stream) {
    const float* X    = (const float*)d_in[0];
    const float* WQ   = (const float*)d_in[1];
    const float* WK   = (const float*)d_in[2];
    const float* WV   = (const float*)d_in[3];
    const float* WG   = (const float*)d_in[4];
    const float* WO   = (const float*)d_in[5];
    const float* GNW  = (const float*)d_in[6];
    const float* GNB  = (const float*)d_in[7];
    const float* LN1W = (const float*)d_in[8];
    const float* LN1B = (const float*)d_in[9];
    const float* LN2W = (const float*)d_in[10];
    const float* LN2B = (const float*)d_in[11];
    const float* FW1  = (const float*)d_in[12];
    const float* FB1  = (const float*)d_in[13];
    const float* FW2  = (const float*)d_in[14];
    const float* FB2  = (const float*)d_in[15];

    char* ws = (char*)d_ws;
    size_t off = 0;
    auto alloc = [&](size_t n) { char* p = ws + off; off += (n + 255) & ~(size_t)255; return p; };

    u16*   WBT  = (u16*)alloc((size_t)LYR * 2048 * 512 * 2);
    u16*   WOT  = (u16*)alloc((size_t)LYR * 512 * 512 * 2);
    u16*   W1T  = (u16*)alloc((size_t)LYR * 2048 * 512 * 2);
    u16*   W2T  = (u16*)alloc((size_t)LYR * 512 * 2048 * 2);
    float4* TAB4 = (float4*)alloc((size_t)2048 * 32 * 16);
    float* XB   = (float*)alloc((size_t)NROWS * DM * 4);
    u16*   XN   = (u16*)alloc((size_t)NROWS * DM * 2);
    u16*   FF1  = (u16*)alloc((size_t)NROWS * 2048 * 2);
    u16*   GB   = (u16*)alloc((size_t)NROWS * DM * 2);
    u16*   QBp  = (u16*)alloc((size_t)NROWS * DM * 2);
    u16*   KBp  = (u16*)alloc((size_t)NROWS * DM * 2);
    u16*   VTp  = (u16*)alloc((size_t)NROWS * DM * 2);
    u16*   ZB   = (u16*)alloc((size_t)NROWS * DM * 2);
    float* Y1   = (float*)alloc((size_t)NROWS * DM * 4);
    u16*   HB   = QBp;   // alias: QB dead after retention

    xpos_tables<<<256, 256, 0, stream>>>(TAB4);
    prep_qkv<<<dim3(8, 24, LYR), 256, 0, stream>>>(WQ, WK, WV, WBT);
    prep_t<<<dim3(8, 8, LYR), 256, 0, stream>>>(WG, WBT + 1536 * 512, 512, 512,
                                                (long long)512 * 512, (long long)2048 * 512);
    prep_t<<<dim3(8, 8, LYR), 256, 0, stream>>>(WO, WOT, 512, 512,
                                                (long long)512 * 512, (long long)512 * 512);
    prep_t<<<dim3(8, 32, LYR), 256, 0, stream>>>(FW1, W1T, 512, 2048,
                                                 (long long)512 * 2048, (long long)2048 * 512);
    prep_t<<<dim3(32, 8, LYR), 256, 0, stream>>>(FW2, W2T, 2048, 512,
                                                 (long long)2048 * 512, (long long)512 * 2048);

    for (int l = 0; l < LYR; ++l) {
        const float* xsrc = (l == 0) ? X : XB;
        float* xdst = (l == LYR - 1) ? (float*)d_out : XB;
        ln_kernel<<<NROWS / 4, 256, 0, stream>>>(xsrc, LN1W + l * 512, LN1B + l * 512, XN);
        gemm_big<4><<<256, 512, 0, stream>>>(
            XN, WBT + (size_t)l * 2048 * 512, nullptr, nullptr,
            QBp, KBp, VTp, GB, TAB4, NROWS, 2048, 512);
        retention<<<512, 512, 90112, stream>>>(QBp, KBp, VTp, GB,
                                               GNW + l * 512, GNB + l * 512, ZB);
        gemm_bt<64, 128, 1><<<256, 256, 0, stream>>>(
            ZB, WOT + (size_t)l * 512 * 512, nullptr, Y1, xsrc, nullptr, NROWS, 512, 512);
        ln_kernel<<<NROWS / 4, 256, 0, stream>>>(Y1, LN2W + l * 512, LN2B + l * 512, HB);
        gemm_big<2><<<256, 512, 0, stream>>>(
            HB, W1T + (size_t)l * 2048 * 512, FF1, FB1 + l * 2048,
            nullptr, nullptr, nullptr, nullptr, nullptr, NROWS, 2048, 512);
        gemm_bt<64, 128, 3><<<256, 256, 0, stream>>>(
            FF1, W2T + (size_t)l * 512 * 2048, nullptr, xdst, Y1, FB2 + l * 512, NROWS, 512, 2048);
    }
}